// Round 3
// baseline (291.186 us; speedup 1.0000x reference)
//
#include <hip/hip_runtime.h>
#include <hip/hip_fp8.h>
#include <math.h>

#define N_NODES 100000
#define DIM 64
#define NUM_LAYER 3
#define BATCH 4096
#define REG_WEIGHT 1e-4f
#define NBUCKET 391                            // dst >> 8 buckets (256 nodes each)
#define STAGE_CAP 4096                         // fixed staging capacity per bucket (14 sigma)
#define CURPAD 16                              // ints: 64B pad per bucket cursor
#define H_SCALE 64.0f
#define H_INV_SCALE (1.0f / 64.0f)

typedef float floatx2 __attribute__((ext_vector_type(2)));

// Scratch as device globals. Self-cleaning invariants (for graph replay):
//  - g_bcur: RELATIVE cursors, all-zero before stage_buckets. Zero-init on load
//    satisfies run 0; pull_layer_fp8(do_gather=1) re-zeros after finalize_place.
//  - g_shead: 0-sentinel (stores idx+1). Zero = empty. pull_layer_fp8 clears
//    after walking each node's chain.
// DIAGNOSTIC ROUND: the heavy 4-kernel prefix is launched TWICE (provably
// output-identical, see launcher) to measure slope vs fixed-floor of dur_us.
__device__ unsigned char g_hf8[2][(size_t)N_NODES * DIM]; // fp8 ping-pong h (scaled)
__device__ float g_sums[(size_t)3 * BATCH * DIM];  // sampled-row accumulators (f32)
__device__ int   g_row_ptr[N_NODES + 1];           // CSR row offsets (by dst)
__device__ float g_dinv[N_NODES];                  // deg^-0.5 (400 KB, L2-resident)
__device__ int   g_bcur[NBUCKET * CURPAD];         // padded bucket staging cursors (relative)
__device__ unsigned int g_stage[NBUCKET * STAGE_CAP]; // packed (src<<8)|(dst&255), 4B/edge
__device__ int   g_csr[1280000];                   // final CSR: src only, 4B/edge
__device__ int   g_shead[N_NODES];                 // node -> first sample idx+1 (0 = none)
__device__ int   g_snext[3 * BATCH];               // sample chain links (idx+1, 0 = end)
__device__ float g_part_sp[BATCH];                 // per-wave softplus partials
__device__ float g_part_rg[BATCH];                 // per-wave reg partials

// HW packed fp8 (OCP e4m3 on gfx950) converts: 2 values per instruction.
__device__ inline void fma4_fp8(unsigned int d, float w,
                                float& a0, float& a1, float& a2, float& a3) {
    floatx2 lo = __builtin_amdgcn_cvt_pk_f32_fp8((int)d, false);  // bytes 0,1
    floatx2 hi = __builtin_amdgcn_cvt_pk_f32_fp8((int)d, true);   // bytes 2,3
    a0 = fmaf(w, lo.x, a0); a1 = fmaf(w, lo.y, a1);
    a2 = fmaf(w, hi.x, a2); a3 = fmaf(w, hi.y, a3);
}
__device__ inline unsigned int pack4_fp8(float a0, float a1, float a2, float a3) {
    int w = __builtin_amdgcn_cvt_pk_fp8_f32(a0, a1, 0, false);
    w     = __builtin_amdgcn_cvt_pk_fp8_f32(a2, a3, w, true);
    return (unsigned int)w;
}

// ---- stage pass (FUSED with emb->fp8 conversion): LDS histogram -> padded
//      global reservations -> sequential-run 4B stores. Also builds the sample
//      chain map (0-sentinel; relies on self-cleaned g_shead). ----
#define EDGES_PER_THREAD 8
__global__ void __launch_bounds__(1024) stage_buckets(const int* __restrict__ src,
                                                      const int* __restrict__ dst, int E,
                                                      const int* __restrict__ users,
                                                      const int* __restrict__ pos,
                                                      const int* __restrict__ neg,
                                                      const float* __restrict__ emb) {
    __shared__ int h[NBUCKET];
    __shared__ int cur[NBUCKET];
    int tid = threadIdx.x;
    int gt = blockIdx.x * 1024 + tid;
    if (gt < 3 * BATCH) {                       // build sample chains (12288 items)
        int which = gt / BATCH, s = gt - which * BATCH;
        const int* idx = (which == 0) ? users : ((which == 1) ? pos : neg);
        g_snext[gt] = atomicExch(&g_shead[idx[s]], gt + 1);   // 0-sentinel links
    }
    int base = blockIdx.x * (1024 * EDGES_PER_THREAD);
    for (int i = tid; i < NBUCKET; i += 1024) h[i] = 0;
    __syncthreads();
    int myd[EDGES_PER_THREAD], mys[EDGES_PER_THREAD];
    #pragma unroll
    for (int k = 0; k < EDGES_PER_THREAD; ++k) {
        int e = base + k * 1024 + tid;
        if (e < E) {
            myd[k] = dst[e]; mys[k] = src[e];
            atomicAdd(&h[myd[k] >> 8], 1);
        } else myd[k] = -1;
    }
    __syncthreads();
    for (int i = tid; i < NBUCKET; i += 1024) {
        int c = h[i];
        // relative reservation + absolute bucket base
        cur[i] = c ? (atomicAdd(&g_bcur[i * CURPAD], c) + i * STAGE_CAP) : 0;
    }
    __syncthreads();
    #pragma unroll
    for (int k = 0; k < EDGES_PER_THREAD; ++k) {
        if (myd[k] >= 0) {
            int p = atomicAdd(&cur[myd[k] >> 8], 1);          // LDS cursor -> slot
            g_stage[p] = (unsigned int)((mys[k] << 8) | (myd[k] & 255));
        }
    }
    // fused prelude: emb -> fp8 (HW cvt, dword stores); grid-stride over rows
    {
        const int NW = N_NODES * DIM / 4;
        int stride = gridDim.x * 1024;
        unsigned int* hw = (unsigned int*)g_hf8[0];
        for (int k = blockIdx.x * 1024 + tid; k < NW; k += stride) {
            const float* e = emb + (size_t)k * 4;
            hw[k] = pack4_fp8(e[0] * H_SCALE, e[1] * H_SCALE,
                              e[2] * H_SCALE, e[3] * H_SCALE);
        }
    }
}

// ---- fused per-bucket: 391-scan for base + degree hist + scan -> row_ptr/dinv,
//      then scatter into the bucket's CSR window (src only, 4B). NO global atomics. ----
__global__ void __launch_bounds__(512) finalize_place() {
    __shared__ int cs[512];
    __shared__ int lh[256], sc[256], cur[256];
    int b = blockIdx.x, t = threadIdx.x;
    int c = (t < NBUCKET) ? g_bcur[t * CURPAD] : 0;           // relative counts
    cs[t] = c;
    __syncthreads();
    for (int off = 1; off < 512; off <<= 1) {
        int x = (t >= off) ? cs[t - off] : 0;
        __syncthreads();
        cs[t] += x;
        __syncthreads();
    }
    int mybase = (b > 0) ? cs[b - 1] : 0;         // exclusive prefix at bucket b
    int cnt    = cs[b] - mybase;
    if (b == 0 && t == 0) g_row_ptr[N_NODES] = cs[NBUCKET - 1];
    int sbeg = b * STAGE_CAP;
    if (t < 256) lh[t] = 0;
    __syncthreads();
    for (int k = t; k < cnt; k += 512)
        atomicAdd(&lh[g_stage[sbeg + k] & 255], 1);
    __syncthreads();
    int v = 0;
    if (t < 256) { v = lh[t]; sc[t] = v; }
    __syncthreads();
    for (int off = 1; off < 256; off <<= 1) {
        int x = (t >= off && t < 256) ? sc[t - off] : 0;
        __syncthreads();
        if (t < 256) sc[t] += x;
        __syncthreads();
    }
    if (t < 256) {
        int start = mybase + sc[t] - v;
        cur[t] = start;
        int node = (b << 8) + t;
        if (node < N_NODES) {
            g_row_ptr[node] = start;                          // exclusive
            g_dinv[node]    = (v > 0) ? rsqrtf((float)v) : 0.0f;
        }
    }
    __syncthreads();
    for (int k = t; k < cnt; k += 512) {                      // staged chunk is L2-hot
        unsigned int e = g_stage[sbeg + k];
        int pos = atomicAdd(&cur[e & 255], 1);
        g_csr[pos] = (int)(e >> 8);                           // src only
    }
}

// ---- pull one layer, TWO nodes per wave: interleaved gathers double per-lane MLP
//      (8 loads in flight). HW fp8 decode; w on the fly from L2-resident dinv.
//      Layer 1 (do_gather=1) additionally restores the self-clean invariants:
//      g_bcur -> 0 and g_shead -> 0 (after consuming chains). ----
__global__ void pull_layer_fp8(const unsigned char* __restrict__ h,
                               unsigned char* __restrict__ hn, int do_gather) {
    int gid0 = blockIdx.x * blockDim.x + threadIdx.x;
    if (do_gather && gid0 < NBUCKET) g_bcur[gid0 * CURPAD] = 0;  // reset for next replay
    int wid  = gid0 >> 6;
    int lane = threadIdx.x & 63;
    int nA = wid * 2, nB = nA + 1;
    if (nA >= N_NODES) return;
    bool hasB = (nB < N_NODES);
    int g  = lane >> 4;      // group 0..3 (edge slot)
    int li = lane & 15;      // dword index in row
    int begA = g_row_ptr[nA], endA = g_row_ptr[nA + 1];
    int begB = hasB ? g_row_ptr[nB] : 0, endB = hasB ? g_row_ptr[nB + 1] : 0;
    float dinvA = g_dinv[nA];
    float dinvB = hasB ? g_dinv[nB] : 0.0f;
    int lenA = endA - begA, lenB = endB - begB;
    int maxLen = max(lenA, lenB);
    float aA0 = 0.f, aA1 = 0.f, aA2 = 0.f, aA3 = 0.f;
    float aB0 = 0.f, aB1 = 0.f, aB2 = 0.f, aB3 = 0.f;
    for (int off = 0; off < maxLen; off += 64) {
        int kA = off + lane;
        int sA = 0; float wA = 0.0f;
        if (kA < lenA) { sA = g_csr[begA + kA]; wA = g_dinv[sA] * dinvA; }
        int sB = 0; float wB = 0.0f;
        if (kA < lenB) { sB = g_csr[begB + kA]; wB = g_dinv[sB] * dinvB; }
        int cnt = min(64, maxLen - off);
        for (int j = 0; j < cnt; j += 16) {       // max shfl idx = 48+12+3 = 63
            int   sA1 = __shfl(sA, j + g),      sA2 = __shfl(sA, j + 4 + g);
            int   sA3 = __shfl(sA, j + 8 + g),  sA4 = __shfl(sA, j + 12 + g);
            int   sB1 = __shfl(sB, j + g),      sB2 = __shfl(sB, j + 4 + g);
            int   sB3 = __shfl(sB, j + 8 + g),  sB4 = __shfl(sB, j + 12 + g);
            float wA1 = __shfl(wA, j + g),      wA2 = __shfl(wA, j + 4 + g);
            float wA3 = __shfl(wA, j + 8 + g),  wA4 = __shfl(wA, j + 12 + g);
            float wB1 = __shfl(wB, j + g),      wB2 = __shfl(wB, j + 4 + g);
            float wB3 = __shfl(wB, j + 8 + g),  wB4 = __shfl(wB, j + 12 + g);
            // 8 independent gathers in flight before first consume
            unsigned int dA1 = *(const unsigned int*)(h + (size_t)sA1 * DIM + li * 4);
            unsigned int dA2 = *(const unsigned int*)(h + (size_t)sA2 * DIM + li * 4);
            unsigned int dA3 = *(const unsigned int*)(h + (size_t)sA3 * DIM + li * 4);
            unsigned int dA4 = *(const unsigned int*)(h + (size_t)sA4 * DIM + li * 4);
            unsigned int dB1 = *(const unsigned int*)(h + (size_t)sB1 * DIM + li * 4);
            unsigned int dB2 = *(const unsigned int*)(h + (size_t)sB2 * DIM + li * 4);
            unsigned int dB3 = *(const unsigned int*)(h + (size_t)sB3 * DIM + li * 4);
            unsigned int dB4 = *(const unsigned int*)(h + (size_t)sB4 * DIM + li * 4);
            fma4_fp8(dA1, wA1, aA0, aA1, aA2, aA3);
            fma4_fp8(dA2, wA2, aA0, aA1, aA2, aA3);
            fma4_fp8(dA3, wA3, aA0, aA1, aA2, aA3);
            fma4_fp8(dA4, wA4, aA0, aA1, aA2, aA3);
            fma4_fp8(dB1, wB1, aB0, aB1, aB2, aB3);
            fma4_fp8(dB2, wB2, aB0, aB1, aB2, aB3);
            fma4_fp8(dB3, wB3, aB0, aB1, aB2, aB3);
            fma4_fp8(dB4, wB4, aB0, aB1, aB2, aB3);
        }
    }
    #pragma unroll
    for (int off = 16; off < 64; off <<= 1) {
        aA0 += __shfl_xor(aA0, off); aA1 += __shfl_xor(aA1, off);
        aA2 += __shfl_xor(aA2, off); aA3 += __shfl_xor(aA3, off);
        aB0 += __shfl_xor(aB0, off); aB1 += __shfl_xor(aB1, off);
        aB2 += __shfl_xor(aB2, off); aB3 += __shfl_xor(aB3, off);
    }
    if (lane < 16) {
        *(unsigned int*)(hn + (size_t)nA * DIM + li * 4) = pack4_fp8(aA0, aA1, aA2, aA3);
        if (hasB)
            *(unsigned int*)(hn + (size_t)nB * DIM + li * 4) = pack4_fp8(aB0, aB1, aB2, aB3);
    }
    if (do_gather) {
        int sidx = g_shead[nA];                  // wave-uniform chain walks (idx+1)
        while (sidx > 0) {
            int sreal = sidx - 1;
            if (lane < 16) {
                float* sp = &g_sums[(size_t)sreal * DIM + li * 4];
                sp[0] = aA0 * H_INV_SCALE; sp[1] = aA1 * H_INV_SCALE;
                sp[2] = aA2 * H_INV_SCALE; sp[3] = aA3 * H_INV_SCALE;
            }
            sidx = g_snext[sreal];
        }
        if (lane == 0) g_shead[nA] = 0;          // restore empty state for next replay
        if (hasB) {
            sidx = g_shead[nB];
            while (sidx > 0) {
                int sreal = sidx - 1;
                if (lane < 16) {
                    float* sp = &g_sums[(size_t)sreal * DIM + li * 4];
                    sp[0] = aB0 * H_INV_SCALE; sp[1] = aB1 * H_INV_SCALE;
                    sp[2] = aB2 * H_INV_SCALE; sp[3] = aB3 * H_INV_SCALE;
                }
                sidx = g_snext[sreal];
            }
            if (lane == 0) g_shead[nB] = 0;
        }
    }
}

// ---- final layer for sampled rows ONLY, fused with the layer-2 sampled gather ----
__global__ void pull_sampled(const unsigned char* __restrict__ h,
                             const int* __restrict__ users, const int* __restrict__ pos,
                             const int* __restrict__ neg) {
    int wid  = (blockIdx.x * blockDim.x + threadIdx.x) >> 6;
    int lane = threadIdx.x & 63;
    if (wid >= 3 * BATCH) return;
    int which = wid / BATCH;
    int i     = wid - which * BATCH;
    const int* idx = (which == 0) ? users : ((which == 1) ? pos : neg);
    int node = idx[i];
    int g  = lane >> 4;
    int li = lane & 15;
    int beg = g_row_ptr[node], end = g_row_ptr[node + 1];
    float dinv_d = g_dinv[node];
    float a0 = 0.f, a1 = 0.f, a2 = 0.f, a3 = 0.f;
    for (int base = beg; base < end; base += 64) {
        int k = base + lane;
        int s = 0; float w = 0.0f;
        if (k < end) { s = g_csr[k]; w = g_dinv[s] * dinv_d; }
        int cnt = min(64, end - base);
        for (int j = 0; j < cnt; j += 16) {
            int   sA = __shfl(s, j + g),      sB = __shfl(s, j + 4 + g);
            int   sC = __shfl(s, j + 8 + g),  sD = __shfl(s, j + 12 + g);
            float wA = __shfl(w, j + g),      wB = __shfl(w, j + 4 + g);
            float wC = __shfl(w, j + 8 + g),  wD = __shfl(w, j + 12 + g);
            unsigned int dA = *(const unsigned int*)(h + (size_t)sA * DIM + li * 4);
            unsigned int dB = *(const unsigned int*)(h + (size_t)sB * DIM + li * 4);
            unsigned int dC = *(const unsigned int*)(h + (size_t)sC * DIM + li * 4);
            unsigned int dD = *(const unsigned int*)(h + (size_t)sD * DIM + li * 4);
            fma4_fp8(dA, wA, a0, a1, a2, a3);
            fma4_fp8(dB, wB, a0, a1, a2, a3);
            fma4_fp8(dC, wC, a0, a1, a2, a3);
            fma4_fp8(dD, wD, a0, a1, a2, a3);
        }
    }
    #pragma unroll
    for (int off = 16; off < 64; off <<= 1) {
        a0 += __shfl_xor(a0, off);
        a1 += __shfl_xor(a1, off);
        a2 += __shfl_xor(a2, off);
        a3 += __shfl_xor(a3, off);
    }
    if (lane < 16) {
        unsigned int dn = *(const unsigned int*)(h + (size_t)node * DIM + li * 4);
        floatx2 lo = __builtin_amdgcn_cvt_pk_f32_fp8((int)dn, false);
        floatx2 hi = __builtin_amdgcn_cvt_pk_f32_fp8((int)dn, true);
        float* sp = &g_sums[(size_t)wid * DIM + li * 4];
        sp[0] += (a0 + lo.x) * H_INV_SCALE;
        sp[1] += (a1 + lo.y) * H_INV_SCALE;
        sp[2] += (a2 + hi.x) * H_INV_SCALE;
        sp[3] += (a3 + hi.y) * H_INV_SCALE;
    }
}

// ---- per-sample scores + reg; layer-0 (emb) folded in here via u0/p0/n0 ----
__global__ void score_reduce(const float* __restrict__ emb,
                             const int* __restrict__ users, const int* __restrict__ pos,
                             const int* __restrict__ neg) {
    int wid  = (blockIdx.x * blockDim.x + threadIdx.x) >> 6;
    int lane = threadIdx.x & 63;
    if (wid >= BATCH) return;
    float u0 = emb[(size_t)users[wid] * DIM + lane];
    float p0 = emb[(size_t)pos[wid]   * DIM + lane];
    float n0 = emb[(size_t)neg[wid]   * DIM + lane];
    float u = 0.25f * (g_sums[(size_t)wid * DIM + lane] + u0);
    float p = 0.25f * (g_sums[(size_t)(BATCH + wid) * DIM + lane] + p0);
    float n = 0.25f * (g_sums[(size_t)(2 * BATCH + wid) * DIM + lane] + n0);
    float ps = u * p;
    float ns = u * n;
    float rg = u0 * u0 + p0 * p0 + n0 * n0;
    #pragma unroll
    for (int off = 32; off > 0; off >>= 1) {
        ps += __shfl_down(ps, off);
        ns += __shfl_down(ns, off);
        rg += __shfl_down(rg, off);
    }
    if (lane == 0) {
        float x  = ns - ps;
        float sp = fmaxf(x, 0.0f) + log1pf(expf(-fabsf(x)));  // stable softplus
        g_part_sp[wid] = sp;
        g_part_rg[wid] = rg;
    }
}

// ---- single-block final reduction over the 4096 per-wave partials ----
__global__ void final_reduce(float* __restrict__ out) {
    __shared__ float s_sp[256], s_rg[256];
    int t = threadIdx.x;
    float sp = 0.0f, rg = 0.0f;
    for (int i = t; i < BATCH; i += 256) { sp += g_part_sp[i]; rg += g_part_rg[i]; }
    s_sp[t] = sp; s_rg[t] = rg;
    __syncthreads();
    for (int off = 128; off > 0; off >>= 1) {
        if (t < off) { s_sp[t] += s_sp[t + off]; s_rg[t] += s_rg[t + off]; }
        __syncthreads();
    }
    if (t == 0) {
        float loss_emb = s_sp[0] / (float)BATCH;
        float reg      = 0.5f * s_rg[0] / (float)BATCH * REG_WEIGHT;
        out[0] = loss_emb + reg;
        out[1] = loss_emb;
        out[2] = reg;
    }
}

extern "C" void kernel_launch(void* const* d_in, const int* in_sizes, int n_in,
                              void* d_out, int out_size, void* d_ws, size_t ws_size,
                              hipStream_t stream) {
    const float* emb   = (const float*)d_in[0];
    const int*   src   = (const int*)d_in[1];
    const int*   dst   = (const int*)d_in[2];
    const int*   users = (const int*)d_in[3];
    const int*   pos   = (const int*)d_in[4];
    const int*   neg   = (const int*)d_in[5];
    const int E = in_sizes[1];
    float* out = (float*)d_out;

    unsigned char* hf_a;  hipGetSymbolAddress((void**)&hf_a, HIP_SYMBOL(g_hf8));
    unsigned char* hf_b = hf_a + (size_t)N_NODES * DIM;

    const int STAGE_BLOCKS = (E + 1024 * EDGES_PER_THREAD - 1) / (1024 * EDGES_PER_THREAD);
    const int NPAIR = (N_NODES + 1) / 2;           // 2 nodes per wave
    const int PULL_BLOCKS = (NPAIR * 64 + 255) / 256;

    // ---- pipeline copy 1 (diagnostic duplicate; outputs fully recomputed by copy 2) ----
    stage_buckets<<<STAGE_BLOCKS, 1024, 0, stream>>>(src, dst, E, users, pos, neg, emb);
    finalize_place<<<NBUCKET, 512, 0, stream>>>();
    pull_layer_fp8<<<PULL_BLOCKS, 256, 0, stream>>>(hf_a, hf_b, 1); // resets bcur/shead
    pull_layer_fp8<<<PULL_BLOCKS, 256, 0, stream>>>(hf_b, hf_a, 0);

    // ---- pipeline copy 2: bcur=0 and shead=0 restored by copy-1's pull1;
    //      stage re-converts emb -> hf_a (overwriting copy-1's h2);
    //      identical CSR/dinv/chains -> identical g_sums and h tensors. ----
    stage_buckets<<<STAGE_BLOCKS, 1024, 0, stream>>>(src, dst, E, users, pos, neg, emb);
    finalize_place<<<NBUCKET, 512, 0, stream>>>();
    pull_layer_fp8<<<PULL_BLOCKS, 256, 0, stream>>>(hf_a, hf_b, 1);
    pull_layer_fp8<<<PULL_BLOCKS, 256, 0, stream>>>(hf_b, hf_a, 0);

    // layer 3 sampled pull + fused layer-2 sampled gather
    pull_sampled<<<(3 * BATCH * 64 + 255) / 256, 256, 0, stream>>>(hf_a, users, pos, neg);

    score_reduce<<<(BATCH * 64 + 255) / 256, 256, 0, stream>>>(emb, users, pos, neg);
    final_reduce<<<1, 256, 0, stream>>>(out);
}

// Round 4
// 187.408 us; speedup vs baseline: 1.5538x; 1.5538x over previous
//
#include <hip/hip_runtime.h>
#include <hip/hip_fp8.h>
#include <math.h>

#define N_NODES 100000
#define DIM 64
#define NUM_LAYER 3
#define BATCH 4096
#define REG_WEIGHT 1e-4f
#define NBUCKET 391                            // dst >> 8 buckets (256 nodes each)
#define STAGE_CAP 4096                         // fixed staging capacity per bucket (14 sigma)
#define CURPAD 16                              // ints: 64B pad per bucket cursor
#define H_SCALE 64.0f
#define H_INV_SCALE (1.0f / 64.0f)

typedef float floatx2 __attribute__((ext_vector_type(2)));

// Scratch as device globals. Self-cleaning invariants (for graph replay):
//  - g_bcur: RELATIVE cursors, all-zero before stage_buckets. Zero-init on load
//    satisfies run 0; pull_layer_fp8(do_gather=1) re-zeros after finalize_place.
//  - g_shead: 0-sentinel (stores idx+1). Zero = empty. pull_layer_fp8 clears
//    after walking each node's chain.
// R3 findings: heavy prefix {stage,finalize,pull,pull} = 98.6us; fixed floor
// ~80us (2x 256MiB harness poison fills inside timed region) + ~12us tails.
// R4: pull restructure -> 4 nodes/wave, group-uniform (src,w) int2 CSR loads,
// no shfl broadcast, no epilogue reduce.
__device__ unsigned char g_hf8[2][(size_t)N_NODES * DIM]; // fp8 ping-pong h (scaled)
__device__ float g_sums[(size_t)3 * BATCH * DIM];  // sampled-row accumulators (f32)
__device__ int   g_row_ptr[N_NODES + 1];           // CSR row offsets (by dst)
__device__ float g_dinv[N_NODES];                  // deg^-0.5 (400 KB, L2-resident)
__device__ int   g_bcur[NBUCKET * CURPAD];         // padded bucket staging cursors (relative)
__device__ unsigned int g_stage[NBUCKET * STAGE_CAP]; // packed (src<<8)|(dst&255), 4B/edge
__device__ int   g_csr[1280000];                   // final CSR: src only, 4B/edge
__device__ int2  g_csr2[1280000];                  // weighted CSR: {src, dinv[src]}, 8B/edge
__device__ int   g_shead[N_NODES];                 // node -> first sample idx+1 (0 = none)
__device__ int   g_snext[3 * BATCH];               // sample chain links (idx+1, 0 = end)
__device__ float g_part_sp[BATCH];                 // per-wave softplus partials
__device__ float g_part_rg[BATCH];                 // per-wave reg partials

// HW packed fp8 (OCP e4m3 on gfx950) converts: 2 values per instruction.
__device__ inline void fma4_fp8(unsigned int d, float w,
                                float& a0, float& a1, float& a2, float& a3) {
    floatx2 lo = __builtin_amdgcn_cvt_pk_f32_fp8((int)d, false);  // bytes 0,1
    floatx2 hi = __builtin_amdgcn_cvt_pk_f32_fp8((int)d, true);   // bytes 2,3
    a0 = fmaf(w, lo.x, a0); a1 = fmaf(w, lo.y, a1);
    a2 = fmaf(w, hi.x, a2); a3 = fmaf(w, hi.y, a3);
}
__device__ inline unsigned int pack4_fp8(float a0, float a1, float a2, float a3) {
    int w = __builtin_amdgcn_cvt_pk_fp8_f32(a0, a1, 0, false);
    w     = __builtin_amdgcn_cvt_pk_fp8_f32(a2, a3, w, true);
    return (unsigned int)w;
}

// ---- stage pass (FUSED with emb->fp8 conversion): LDS histogram -> padded
//      global reservations -> sequential-run 4B stores. Also builds the sample
//      chain map (0-sentinel; relies on self-cleaned g_shead). ----
#define EDGES_PER_THREAD 8
__global__ void __launch_bounds__(1024) stage_buckets(const int* __restrict__ src,
                                                      const int* __restrict__ dst, int E,
                                                      const int* __restrict__ users,
                                                      const int* __restrict__ pos,
                                                      const int* __restrict__ neg,
                                                      const float* __restrict__ emb) {
    __shared__ int h[NBUCKET];
    __shared__ int cur[NBUCKET];
    int tid = threadIdx.x;
    int gt = blockIdx.x * 1024 + tid;
    if (gt < 3 * BATCH) {                       // build sample chains (12288 items)
        int which = gt / BATCH, s = gt - which * BATCH;
        const int* idx = (which == 0) ? users : ((which == 1) ? pos : neg);
        g_snext[gt] = atomicExch(&g_shead[idx[s]], gt + 1);   // 0-sentinel links
    }
    int base = blockIdx.x * (1024 * EDGES_PER_THREAD);
    for (int i = tid; i < NBUCKET; i += 1024) h[i] = 0;
    __syncthreads();
    int myd[EDGES_PER_THREAD], mys[EDGES_PER_THREAD];
    #pragma unroll
    for (int k = 0; k < EDGES_PER_THREAD; ++k) {
        int e = base + k * 1024 + tid;
        if (e < E) {
            myd[k] = dst[e]; mys[k] = src[e];
            atomicAdd(&h[myd[k] >> 8], 1);
        } else myd[k] = -1;
    }
    __syncthreads();
    for (int i = tid; i < NBUCKET; i += 1024) {
        int c = h[i];
        // relative reservation + absolute bucket base
        cur[i] = c ? (atomicAdd(&g_bcur[i * CURPAD], c) + i * STAGE_CAP) : 0;
    }
    __syncthreads();
    #pragma unroll
    for (int k = 0; k < EDGES_PER_THREAD; ++k) {
        if (myd[k] >= 0) {
            int p = atomicAdd(&cur[myd[k] >> 8], 1);          // LDS cursor -> slot
            g_stage[p] = (unsigned int)((mys[k] << 8) | (myd[k] & 255));
        }
    }
    // fused prelude: emb -> fp8 (HW cvt, dword stores); grid-stride over rows
    {
        const int NW = N_NODES * DIM / 4;
        int stride = gridDim.x * 1024;
        unsigned int* hw = (unsigned int*)g_hf8[0];
        for (int k = blockIdx.x * 1024 + tid; k < NW; k += stride) {
            const float* e = emb + (size_t)k * 4;
            hw[k] = pack4_fp8(e[0] * H_SCALE, e[1] * H_SCALE,
                              e[2] * H_SCALE, e[3] * H_SCALE);
        }
    }
}

// ---- fused per-bucket: 391-scan for base + degree hist + scan -> row_ptr/dinv,
//      then scatter into the bucket's CSR window (src only, 4B). NO global atomics. ----
__global__ void __launch_bounds__(512) finalize_place() {
    __shared__ int cs[512];
    __shared__ int lh[256], sc[256], cur[256];
    int b = blockIdx.x, t = threadIdx.x;
    int c = (t < NBUCKET) ? g_bcur[t * CURPAD] : 0;           // relative counts
    cs[t] = c;
    __syncthreads();
    for (int off = 1; off < 512; off <<= 1) {
        int x = (t >= off) ? cs[t - off] : 0;
        __syncthreads();
        cs[t] += x;
        __syncthreads();
    }
    int mybase = (b > 0) ? cs[b - 1] : 0;         // exclusive prefix at bucket b
    int cnt    = cs[b] - mybase;
    if (b == 0 && t == 0) g_row_ptr[N_NODES] = cs[NBUCKET - 1];
    int sbeg = b * STAGE_CAP;
    if (t < 256) lh[t] = 0;
    __syncthreads();
    for (int k = t; k < cnt; k += 512)
        atomicAdd(&lh[g_stage[sbeg + k] & 255], 1);
    __syncthreads();
    int v = 0;
    if (t < 256) { v = lh[t]; sc[t] = v; }
    __syncthreads();
    for (int off = 1; off < 256; off <<= 1) {
        int x = (t >= off && t < 256) ? sc[t - off] : 0;
        __syncthreads();
        if (t < 256) sc[t] += x;
        __syncthreads();
    }
    if (t < 256) {
        int start = mybase + sc[t] - v;
        cur[t] = start;
        int node = (b << 8) + t;
        if (node < N_NODES) {
            g_row_ptr[node] = start;                          // exclusive
            g_dinv[node]    = (v > 0) ? rsqrtf((float)v) : 0.0f;
        }
    }
    __syncthreads();
    for (int k = t; k < cnt; k += 512) {                      // staged chunk is L2-hot
        unsigned int e = g_stage[sbeg + k];
        int pos = atomicAdd(&cur[e & 255], 1);
        g_csr[pos] = (int)(e >> 8);                           // src only
    }
}

// ---- weighted-CSR build: csr2[i] = {src, dinv[src]} (dst-side dinv is applied
//      per-node in the pulls as a group-uniform scalar). Must run after
//      finalize_place (needs complete g_csr + g_dinv). Coalesced 8B writes. ----
__global__ void build_wcsr(int E) {
    int i = blockIdx.x * blockDim.x + threadIdx.x;
    if (i < E) {
        int s = g_csr[i];
        g_csr2[i] = make_int2(s, __float_as_int(g_dinv[s]));
    }
}

// ---- pull one layer, FOUR nodes per wave (one 16-lane group per node; a row
//      is exactly 16 dwords). Edge stream is group-uniform int2 {src, w_src}
//      loads -> no shfl broadcast, no epilogue cross-lane reduce. 4 gathers in
//      flight per step. Layer 1 (do_gather=1) also restores the self-clean
//      invariants: g_bcur -> 0 and g_shead -> 0 (after consuming chains). ----
__global__ void pull_layer_fp8(const unsigned char* __restrict__ h,
                               unsigned char* __restrict__ hn, int do_gather) {
    int gid0 = blockIdx.x * blockDim.x + threadIdx.x;
    if (do_gather && gid0 < NBUCKET) g_bcur[gid0 * CURPAD] = 0;  // reset for next replay
    int wid  = gid0 >> 6;
    int lane = threadIdx.x & 63;
    int g  = lane >> 4;      // group 0..3 -> node
    int li = lane & 15;      // dword index in row
    int n = wid * 4 + g;
    if (n >= N_NODES) return;                    // N_NODES % 4 == 0: whole waves retire
    int beg = g_row_ptr[n], end = g_row_ptr[n + 1];
    float dinvN = g_dinv[n];
    float a0 = 0.f, a1 = 0.f, a2 = 0.f, a3 = 0.f;
    for (int k = beg; k < end; k += 4) {
        int k1 = min(k + 1, end - 1);
        int k2 = min(k + 2, end - 1);
        int k3 = min(k + 3, end - 1);
        int2 e0 = g_csr2[k];
        int2 e1 = g_csr2[k1];
        int2 e2 = g_csr2[k2];
        int2 e3 = g_csr2[k3];
        unsigned int d0 = *(const unsigned int*)(h + (size_t)e0.x * DIM + li * 4);
        unsigned int d1 = *(const unsigned int*)(h + (size_t)e1.x * DIM + li * 4);
        unsigned int d2 = *(const unsigned int*)(h + (size_t)e2.x * DIM + li * 4);
        unsigned int d3 = *(const unsigned int*)(h + (size_t)e3.x * DIM + li * 4);
        float w0 = __int_as_float(e0.y) * dinvN;
        float w1 = (k + 1 < end) ? __int_as_float(e1.y) * dinvN : 0.0f;
        float w2 = (k + 2 < end) ? __int_as_float(e2.y) * dinvN : 0.0f;
        float w3 = (k + 3 < end) ? __int_as_float(e3.y) * dinvN : 0.0f;
        fma4_fp8(d0, w0, a0, a1, a2, a3);
        fma4_fp8(d1, w1, a0, a1, a2, a3);
        fma4_fp8(d2, w2, a0, a1, a2, a3);
        fma4_fp8(d3, w3, a0, a1, a2, a3);
    }
    *(unsigned int*)(hn + (size_t)n * DIM + li * 4) = pack4_fp8(a0, a1, a2, a3);
    if (do_gather) {
        int sidx = g_shead[n];                   // group-uniform chain walk (idx+1)
        while (sidx > 0) {
            int sr = sidx - 1;
            float* sp = &g_sums[(size_t)sr * DIM + li * 4];
            sp[0] = a0 * H_INV_SCALE; sp[1] = a1 * H_INV_SCALE;
            sp[2] = a2 * H_INV_SCALE; sp[3] = a3 * H_INV_SCALE;
            sidx = g_snext[sr];
        }
        if (li == 0) g_shead[n] = 0;             // restore empty state for next replay
    }
}

// ---- final layer for sampled rows ONLY (4 samples/wave, same group scheme),
//      fused with the layer-2 sampled gather (self-term dn = h2[node]). ----
__global__ void pull_sampled(const unsigned char* __restrict__ h,
                             const int* __restrict__ users, const int* __restrict__ pos,
                             const int* __restrict__ neg) {
    int gid0 = blockIdx.x * blockDim.x + threadIdx.x;
    int wid  = gid0 >> 6;
    int lane = threadIdx.x & 63;
    int g  = lane >> 4;
    int li = lane & 15;
    int s = wid * 4 + g;
    if (s >= 3 * BATCH) return;
    int which = s >> 12;                         // / BATCH (4096)
    int i     = s & (BATCH - 1);
    const int* idx = (which == 0) ? users : ((which == 1) ? pos : neg);
    int node = idx[i];
    int beg = g_row_ptr[node], end = g_row_ptr[node + 1];
    float dinvN = g_dinv[node];
    float a0 = 0.f, a1 = 0.f, a2 = 0.f, a3 = 0.f;
    for (int k = beg; k < end; k += 4) {
        int k1 = min(k + 1, end - 1);
        int k2 = min(k + 2, end - 1);
        int k3 = min(k + 3, end - 1);
        int2 e0 = g_csr2[k];
        int2 e1 = g_csr2[k1];
        int2 e2 = g_csr2[k2];
        int2 e3 = g_csr2[k3];
        unsigned int d0 = *(const unsigned int*)(h + (size_t)e0.x * DIM + li * 4);
        unsigned int d1 = *(const unsigned int*)(h + (size_t)e1.x * DIM + li * 4);
        unsigned int d2 = *(const unsigned int*)(h + (size_t)e2.x * DIM + li * 4);
        unsigned int d3 = *(const unsigned int*)(h + (size_t)e3.x * DIM + li * 4);
        float w0 = __int_as_float(e0.y) * dinvN;
        float w1 = (k + 1 < end) ? __int_as_float(e1.y) * dinvN : 0.0f;
        float w2 = (k + 2 < end) ? __int_as_float(e2.y) * dinvN : 0.0f;
        float w3 = (k + 3 < end) ? __int_as_float(e3.y) * dinvN : 0.0f;
        fma4_fp8(d0, w0, a0, a1, a2, a3);
        fma4_fp8(d1, w1, a0, a1, a2, a3);
        fma4_fp8(d2, w2, a0, a1, a2, a3);
        fma4_fp8(d3, w3, a0, a1, a2, a3);
    }
    unsigned int dn = *(const unsigned int*)(h + (size_t)node * DIM + li * 4);
    floatx2 lo = __builtin_amdgcn_cvt_pk_f32_fp8((int)dn, false);
    floatx2 hi = __builtin_amdgcn_cvt_pk_f32_fp8((int)dn, true);
    float* sp = &g_sums[(size_t)s * DIM + li * 4];
    sp[0] += (a0 + lo.x) * H_INV_SCALE;
    sp[1] += (a1 + lo.y) * H_INV_SCALE;
    sp[2] += (a2 + hi.x) * H_INV_SCALE;
    sp[3] += (a3 + hi.y) * H_INV_SCALE;
}

// ---- per-sample scores + reg; layer-0 (emb) folded in here via u0/p0/n0 ----
__global__ void score_reduce(const float* __restrict__ emb,
                             const int* __restrict__ users, const int* __restrict__ pos,
                             const int* __restrict__ neg) {
    int wid  = (blockIdx.x * blockDim.x + threadIdx.x) >> 6;
    int lane = threadIdx.x & 63;
    if (wid >= BATCH) return;
    float u0 = emb[(size_t)users[wid] * DIM + lane];
    float p0 = emb[(size_t)pos[wid]   * DIM + lane];
    float n0 = emb[(size_t)neg[wid]   * DIM + lane];
    float u = 0.25f * (g_sums[(size_t)wid * DIM + lane] + u0);
    float p = 0.25f * (g_sums[(size_t)(BATCH + wid) * DIM + lane] + p0);
    float n = 0.25f * (g_sums[(size_t)(2 * BATCH + wid) * DIM + lane] + n0);
    float ps = u * p;
    float ns = u * n;
    float rg = u0 * u0 + p0 * p0 + n0 * n0;
    #pragma unroll
    for (int off = 32; off > 0; off >>= 1) {
        ps += __shfl_down(ps, off);
        ns += __shfl_down(ns, off);
        rg += __shfl_down(rg, off);
    }
    if (lane == 0) {
        float x  = ns - ps;
        float sp = fmaxf(x, 0.0f) + log1pf(expf(-fabsf(x)));  // stable softplus
        g_part_sp[wid] = sp;
        g_part_rg[wid] = rg;
    }
}

// ---- single-block final reduction over the 4096 per-wave partials ----
__global__ void final_reduce(float* __restrict__ out) {
    __shared__ float s_sp[256], s_rg[256];
    int t = threadIdx.x;
    float sp = 0.0f, rg = 0.0f;
    for (int i = t; i < BATCH; i += 256) { sp += g_part_sp[i]; rg += g_part_rg[i]; }
    s_sp[t] = sp; s_rg[t] = rg;
    __syncthreads();
    for (int off = 128; off > 0; off >>= 1) {
        if (t < off) { s_sp[t] += s_sp[t + off]; s_rg[t] += s_rg[t + off]; }
        __syncthreads();
    }
    if (t == 0) {
        float loss_emb = s_sp[0] / (float)BATCH;
        float reg      = 0.5f * s_rg[0] / (float)BATCH * REG_WEIGHT;
        out[0] = loss_emb + reg;
        out[1] = loss_emb;
        out[2] = reg;
    }
}

extern "C" void kernel_launch(void* const* d_in, const int* in_sizes, int n_in,
                              void* d_out, int out_size, void* d_ws, size_t ws_size,
                              hipStream_t stream) {
    const float* emb   = (const float*)d_in[0];
    const int*   src   = (const int*)d_in[1];
    const int*   dst   = (const int*)d_in[2];
    const int*   users = (const int*)d_in[3];
    const int*   pos   = (const int*)d_in[4];
    const int*   neg   = (const int*)d_in[5];
    const int E = in_sizes[1];
    float* out = (float*)d_out;

    unsigned char* hf_a;  hipGetSymbolAddress((void**)&hf_a, HIP_SYMBOL(g_hf8));
    unsigned char* hf_b = hf_a + (size_t)N_NODES * DIM;

    const int STAGE_BLOCKS = (E + 1024 * EDGES_PER_THREAD - 1) / (1024 * EDGES_PER_THREAD);
    stage_buckets<<<STAGE_BLOCKS, 1024, 0, stream>>>(src, dst, E, users, pos, neg, emb);
    finalize_place<<<NBUCKET, 512, 0, stream>>>();
    build_wcsr<<<(E + 255) / 256, 256, 0, stream>>>(E);

    const int NQUAD = (N_NODES + 3) / 4;           // 4 nodes per wave
    const int PULL_BLOCKS = (NQUAD * 64 + 255) / 256;

    // layer 1: full pull + fused sampled gather (assigns g_sums) + invariant restore
    pull_layer_fp8<<<PULL_BLOCKS, 256, 0, stream>>>(hf_a, hf_b, 1);

    // layer 2: full pull (input to layer 3's sampled pull)
    pull_layer_fp8<<<PULL_BLOCKS, 256, 0, stream>>>(hf_b, hf_a, 0);

    // layer 3 sampled pull (4 samples/wave) + fused layer-2 sampled gather
    const int SAMP_BLOCKS = ((3 * BATCH + 3) / 4 * 64 + 255) / 256;
    pull_sampled<<<SAMP_BLOCKS, 256, 0, stream>>>(hf_a, users, pos, neg);

    score_reduce<<<(BATCH * 64 + 255) / 256, 256, 0, stream>>>(emb, users, pos, neg);
    final_reduce<<<1, 256, 0, stream>>>(out);
}

// Round 5
// 185.421 us; speedup vs baseline: 1.5704x; 1.0107x over previous
//
#include <hip/hip_runtime.h>
#include <hip/hip_fp8.h>
#include <math.h>

#define N_NODES 100000
#define DIM 64
#define NUM_LAYER 3
#define BATCH 4096
#define REG_WEIGHT 1e-4f
#define NBUCKET 391                            // dst >> 8 buckets (256 nodes each)
#define STAGE_CAP 4096                         // fixed staging capacity per bucket (14 sigma)
#define CURPAD 16                              // ints: 64B pad per bucket cursor
#define H_SCALE 256.0f                         // fp8 store scale (values pre-scaled by dinv)
#define H_INV_SCALE (1.0f / 256.0f)

typedef float floatx2 __attribute__((ext_vector_type(2)));

// Scratch as device globals. Self-cleaning invariants (for graph replay):
//  - g_bcur: RELATIVE cursors, all-zero before stage_buckets. Zero-init on load
//    satisfies run 0; pull_layer_fp8 layer-1 re-zeros after finalize_place.
//  - g_shead: 0-sentinel (stores idx+1). Zero = empty. pull_layer_fp8 layer-2
//    clears after walking each node's chain (layer-1 walks but keeps chains).
// R3: heavy prefix = ~99us; fixed floor ~80us (2x 256MiB harness poison fills
// in timed region) + ~12us tails. R5: PRE-WEIGHTED fp8 table Hs[u]=dinv[u]*h[u]
// -> per-edge weight gone, src-only 4B CSR, build_wcsr deleted, conversion
// fused into finalize (dinv dependency), stage EPT 8->4 for full CU coverage.
__device__ unsigned char g_hf8[2][(size_t)N_NODES * DIM]; // fp8 ping-pong Hs (scaled)
__device__ float g_sums[(size_t)3 * BATCH * DIM];  // sampled-row accumulators (f32)
__device__ int   g_row_ptr[N_NODES + 1];           // CSR row offsets (by dst)
__device__ float g_dinv[N_NODES];                  // deg^-0.5 (400 KB, L2-resident)
__device__ int   g_bcur[NBUCKET * CURPAD];         // padded bucket staging cursors (relative)
__device__ unsigned int g_stage[NBUCKET * STAGE_CAP]; // packed (src<<8)|(dst&255), 4B/edge
__device__ int   g_csr[1280000];                   // final CSR: src only, 4B/edge
__device__ int   g_shead[N_NODES];                 // node -> first sample idx+1 (0 = none)
__device__ int   g_snext[3 * BATCH];               // sample chain links (idx+1, 0 = end)
__device__ float g_part_sp[BATCH];                 // per-wave softplus partials
__device__ float g_part_rg[BATCH];                 // per-wave reg partials

// HW packed fp8 (OCP e4m3 on gfx950) converts: 2 values per instruction.
__device__ inline void fma4_fp8(unsigned int d, float w,
                                float& a0, float& a1, float& a2, float& a3) {
    floatx2 lo = __builtin_amdgcn_cvt_pk_f32_fp8((int)d, false);  // bytes 0,1
    floatx2 hi = __builtin_amdgcn_cvt_pk_f32_fp8((int)d, true);   // bytes 2,3
    a0 = fmaf(w, lo.x, a0); a1 = fmaf(w, lo.y, a1);
    a2 = fmaf(w, hi.x, a2); a3 = fmaf(w, hi.y, a3);
}
__device__ inline unsigned int pack4_fp8(float a0, float a1, float a2, float a3) {
    int w = __builtin_amdgcn_cvt_pk_fp8_f32(a0, a1, 0, false);
    w     = __builtin_amdgcn_cvt_pk_fp8_f32(a2, a3, w, true);
    return (unsigned int)w;
}

// ---- stage pass: LDS histogram -> padded global reservations -> sequential-run
//      4B stores. Also builds the sample chain map (0-sentinel). EPT=4 -> 313
//      blocks (full 256-CU coverage; 157 blocks at EPT=8 left 99 CUs idle). ----
#define EDGES_PER_THREAD 4
__global__ void __launch_bounds__(1024) stage_buckets(const int* __restrict__ src,
                                                      const int* __restrict__ dst, int E,
                                                      const int* __restrict__ users,
                                                      const int* __restrict__ pos,
                                                      const int* __restrict__ neg) {
    __shared__ int h[NBUCKET];
    __shared__ int cur[NBUCKET];
    int tid = threadIdx.x;
    int gt = blockIdx.x * 1024 + tid;
    if (gt < 3 * BATCH) {                       // build sample chains (12288 items)
        int which = gt / BATCH, s = gt - which * BATCH;
        const int* idx = (which == 0) ? users : ((which == 1) ? pos : neg);
        g_snext[gt] = atomicExch(&g_shead[idx[s]], gt + 1);   // 0-sentinel links
    }
    int base = blockIdx.x * (1024 * EDGES_PER_THREAD);
    for (int i = tid; i < NBUCKET; i += 1024) h[i] = 0;
    __syncthreads();
    int myd[EDGES_PER_THREAD], mys[EDGES_PER_THREAD];
    #pragma unroll
    for (int k = 0; k < EDGES_PER_THREAD; ++k) {
        int e = base + k * 1024 + tid;
        if (e < E) {
            myd[k] = dst[e]; mys[k] = src[e];
            atomicAdd(&h[myd[k] >> 8], 1);
        } else myd[k] = -1;
    }
    __syncthreads();
    for (int i = tid; i < NBUCKET; i += 1024) {
        int c = h[i];
        // relative reservation + absolute bucket base
        cur[i] = c ? (atomicAdd(&g_bcur[i * CURPAD], c) + i * STAGE_CAP) : 0;
    }
    __syncthreads();
    #pragma unroll
    for (int k = 0; k < EDGES_PER_THREAD; ++k) {
        if (myd[k] >= 0) {
            int p = atomicAdd(&cur[myd[k] >> 8], 1);          // LDS cursor -> slot
            g_stage[p] = (unsigned int)((mys[k] << 8) | (myd[k] & 255));
        }
    }
}

// ---- fused per-bucket: 391-scan for base + degree hist + scan -> row_ptr/dinv,
//      scatter into the bucket's CSR window (src only, 4B), THEN convert this
//      bucket's 256 emb rows to the pre-weighted fp8 table Hs0 = dinv*emb
//      (dinv is in LDS; conversion could not live in stage for this reason). ----
__global__ void __launch_bounds__(512) finalize_place(const float* __restrict__ emb) {
    __shared__ int cs[512];
    __shared__ int lh[256], sc[256], cur[256];
    __shared__ float ldv[256];
    int b = blockIdx.x, t = threadIdx.x;
    int c = (t < NBUCKET) ? g_bcur[t * CURPAD] : 0;           // relative counts
    cs[t] = c;
    __syncthreads();
    for (int off = 1; off < 512; off <<= 1) {
        int x = (t >= off) ? cs[t - off] : 0;
        __syncthreads();
        cs[t] += x;
        __syncthreads();
    }
    int mybase = (b > 0) ? cs[b - 1] : 0;         // exclusive prefix at bucket b
    int cnt    = cs[b] - mybase;
    if (b == 0 && t == 0) g_row_ptr[N_NODES] = cs[NBUCKET - 1];
    int sbeg = b * STAGE_CAP;
    if (t < 256) lh[t] = 0;
    __syncthreads();
    for (int k = t; k < cnt; k += 512)
        atomicAdd(&lh[g_stage[sbeg + k] & 255], 1);
    __syncthreads();
    int v = 0;
    if (t < 256) { v = lh[t]; sc[t] = v; }
    __syncthreads();
    for (int off = 1; off < 256; off <<= 1) {
        int x = (t >= off && t < 256) ? sc[t - off] : 0;
        __syncthreads();
        if (t < 256) sc[t] += x;
        __syncthreads();
    }
    if (t < 256) {
        int start = mybase + sc[t] - v;
        cur[t] = start;
        float dv = (v > 0) ? rsqrtf((float)v) : 0.0f;
        ldv[t] = dv;
        int node = (b << 8) + t;
        if (node < N_NODES) {
            g_row_ptr[node] = start;                          // exclusive
            g_dinv[node]    = dv;
        }
    }
    __syncthreads();
    for (int k = t; k < cnt; k += 512) {                      // staged chunk is L2-hot
        unsigned int e = g_stage[sbeg + k];
        int pos = atomicAdd(&cur[e & 255], 1);
        g_csr[pos] = (int)(e >> 8);                           // src only
    }
    // fused conversion: this bucket's rows -> Hs0 = SCALE * dinv[row] * emb[row]
    {
        int nbase = b << 8;
        int rows = N_NODES - nbase; if (rows > 256) rows = 256;
        unsigned int* hw = (unsigned int*)g_hf8[0];
        for (int idx = t; idx < rows * 16; idx += 512) {
            int row = idx >> 4, li = idx & 15;
            const float4 ev = *(const float4*)(emb + (size_t)(nbase + row) * DIM + li * 4);
            float s = ldv[row] * H_SCALE;
            hw[(size_t)(nbase + row) * 16 + li] =
                pack4_fp8(ev.x * s, ev.y * s, ev.z * s, ev.w * s);
        }
    }
}

// ---- pull one layer, FOUR nodes per wave (one 16-lane group per node; a row
//      is exactly 16 dwords). Table is pre-weighted (Hs = dinv*h), so the edge
//      stream is src-only 4B and there is NO per-edge weight: a = sum(decode),
//      store = dinv^2 * a, sampled-gather value = dinv * a / SCALE.
//      mode 1 (layer 1): g_sums = value; resets g_bcur; keeps chains.
//      mode 2 (layer 2): g_sums += value; resets g_shead (consumes chains). ----
__global__ void pull_layer_fp8(const unsigned char* __restrict__ h,
                               unsigned char* __restrict__ hn, int mode) {
    int gid0 = blockIdx.x * blockDim.x + threadIdx.x;
    if (mode == 1 && gid0 < NBUCKET) g_bcur[gid0 * CURPAD] = 0;  // reset for next replay
    int wid  = gid0 >> 6;
    int lane = threadIdx.x & 63;
    int g  = lane >> 4;      // group 0..3 -> node
    int li = lane & 15;      // dword index in row
    int n = wid * 4 + g;
    if (n >= N_NODES) return;                    // N_NODES % 4 == 0: whole waves retire
    int beg = g_row_ptr[n], end = g_row_ptr[n + 1];
    float dinvN = g_dinv[n];
    float a0 = 0.f, a1 = 0.f, a2 = 0.f, a3 = 0.f;
    for (int k = beg; k < end; k += 4) {
        int k1 = min(k + 1, end - 1);
        int k2 = min(k + 2, end - 1);
        int k3 = min(k + 3, end - 1);
        int s0 = g_csr[k];
        int s1 = g_csr[k1];
        int s2 = g_csr[k2];
        int s3 = g_csr[k3];
        unsigned int d0 = *(const unsigned int*)(h + (size_t)s0 * DIM + li * 4);
        unsigned int d1 = *(const unsigned int*)(h + (size_t)s1 * DIM + li * 4);
        unsigned int d2 = *(const unsigned int*)(h + (size_t)s2 * DIM + li * 4);
        unsigned int d3 = *(const unsigned int*)(h + (size_t)s3 * DIM + li * 4);
        float w1 = (k + 1 < end) ? 1.0f : 0.0f;
        float w2 = (k + 2 < end) ? 1.0f : 0.0f;
        float w3 = (k + 3 < end) ? 1.0f : 0.0f;
        fma4_fp8(d0, 1.0f, a0, a1, a2, a3);
        fma4_fp8(d1, w1, a0, a1, a2, a3);
        fma4_fp8(d2, w2, a0, a1, a2, a3);
        fma4_fp8(d3, w3, a0, a1, a2, a3);
    }
    float dd = dinvN * dinvN;                    // store next pre-weighted: dinv^2 * a
    *(unsigned int*)(hn + (size_t)n * DIM + li * 4) =
        pack4_fp8(a0 * dd, a1 * dd, a2 * dd, a3 * dd);
    if (mode) {
        float gw = dinvN * H_INV_SCALE;          // unscaled h value = a * dinv / SCALE
        int sidx = g_shead[n];                   // group-uniform chain walk (idx+1)
        while (sidx > 0) {
            int sr = sidx - 1;
            float* sp = &g_sums[(size_t)sr * DIM + li * 4];
            if (mode == 1) {
                sp[0] = a0 * gw; sp[1] = a1 * gw;
                sp[2] = a2 * gw; sp[3] = a3 * gw;
            } else {
                sp[0] += a0 * gw; sp[1] += a1 * gw;
                sp[2] += a2 * gw; sp[3] += a3 * gw;
            }
            sidx = g_snext[sr];
        }
        if (mode == 2 && li == 0) g_shead[n] = 0; // consume chains on layer 2
    }
}

// ---- final layer for sampled rows ONLY (4 samples/wave, same group scheme).
//      h2 self-term no longer needed here (pull layer-2 accumulated it). ----
__global__ void pull_sampled(const unsigned char* __restrict__ h,
                             const int* __restrict__ users, const int* __restrict__ pos,
                             const int* __restrict__ neg) {
    int gid0 = blockIdx.x * blockDim.x + threadIdx.x;
    int wid  = gid0 >> 6;
    int lane = threadIdx.x & 63;
    int g  = lane >> 4;
    int li = lane & 15;
    int s = wid * 4 + g;
    if (s >= 3 * BATCH) return;
    int which = s >> 12;                         // / BATCH (4096)
    int i     = s & (BATCH - 1);
    const int* idx = (which == 0) ? users : ((which == 1) ? pos : neg);
    int node = idx[i];
    int beg = g_row_ptr[node], end = g_row_ptr[node + 1];
    float dinvN = g_dinv[node];
    float a0 = 0.f, a1 = 0.f, a2 = 0.f, a3 = 0.f;
    for (int k = beg; k < end; k += 4) {
        int k1 = min(k + 1, end - 1);
        int k2 = min(k + 2, end - 1);
        int k3 = min(k + 3, end - 1);
        int s0 = g_csr[k];
        int s1 = g_csr[k1];
        int s2 = g_csr[k2];
        int s3 = g_csr[k3];
        unsigned int d0 = *(const unsigned int*)(h + (size_t)s0 * DIM + li * 4);
        unsigned int d1 = *(const unsigned int*)(h + (size_t)s1 * DIM + li * 4);
        unsigned int d2 = *(const unsigned int*)(h + (size_t)s2 * DIM + li * 4);
        unsigned int d3 = *(const unsigned int*)(h + (size_t)s3 * DIM + li * 4);
        float w1 = (k + 1 < end) ? 1.0f : 0.0f;
        float w2 = (k + 2 < end) ? 1.0f : 0.0f;
        float w3 = (k + 3 < end) ? 1.0f : 0.0f;
        fma4_fp8(d0, 1.0f, a0, a1, a2, a3);
        fma4_fp8(d1, w1, a0, a1, a2, a3);
        fma4_fp8(d2, w2, a0, a1, a2, a3);
        fma4_fp8(d3, w3, a0, a1, a2, a3);
    }
    float gw = dinvN * H_INV_SCALE;
    float* sp = &g_sums[(size_t)s * DIM + li * 4];
    sp[0] += a0 * gw;
    sp[1] += a1 * gw;
    sp[2] += a2 * gw;
    sp[3] += a3 * gw;
}

// ---- per-sample scores + reg; layer-0 (emb) folded in here via u0/p0/n0 ----
__global__ void score_reduce(const float* __restrict__ emb,
                             const int* __restrict__ users, const int* __restrict__ pos,
                             const int* __restrict__ neg) {
    int wid  = (blockIdx.x * blockDim.x + threadIdx.x) >> 6;
    int lane = threadIdx.x & 63;
    if (wid >= BATCH) return;
    float u0 = emb[(size_t)users[wid] * DIM + lane];
    float p0 = emb[(size_t)pos[wid]   * DIM + lane];
    float n0 = emb[(size_t)neg[wid]   * DIM + lane];
    float u = 0.25f * (g_sums[(size_t)wid * DIM + lane] + u0);
    float p = 0.25f * (g_sums[(size_t)(BATCH + wid) * DIM + lane] + p0);
    float n = 0.25f * (g_sums[(size_t)(2 * BATCH + wid) * DIM + lane] + n0);
    float ps = u * p;
    float ns = u * n;
    float rg = u0 * u0 + p0 * p0 + n0 * n0;
    #pragma unroll
    for (int off = 32; off > 0; off >>= 1) {
        ps += __shfl_down(ps, off);
        ns += __shfl_down(ns, off);
        rg += __shfl_down(rg, off);
    }
    if (lane == 0) {
        float x  = ns - ps;
        float sp = fmaxf(x, 0.0f) + log1pf(expf(-fabsf(x)));  // stable softplus
        g_part_sp[wid] = sp;
        g_part_rg[wid] = rg;
    }
}

// ---- single-block final reduction over the 4096 per-wave partials ----
__global__ void final_reduce(float* __restrict__ out) {
    __shared__ float s_sp[256], s_rg[256];
    int t = threadIdx.x;
    float sp = 0.0f, rg = 0.0f;
    for (int i = t; i < BATCH; i += 256) { sp += g_part_sp[i]; rg += g_part_rg[i]; }
    s_sp[t] = sp; s_rg[t] = rg;
    __syncthreads();
    for (int off = 128; off > 0; off >>= 1) {
        if (t < off) { s_sp[t] += s_sp[t + off]; s_rg[t] += s_rg[t + off]; }
        __syncthreads();
    }
    if (t == 0) {
        float loss_emb = s_sp[0] / (float)BATCH;
        float reg      = 0.5f * s_rg[0] / (float)BATCH * REG_WEIGHT;
        out[0] = loss_emb + reg;
        out[1] = loss_emb;
        out[2] = reg;
    }
}

extern "C" void kernel_launch(void* const* d_in, const int* in_sizes, int n_in,
                              void* d_out, int out_size, void* d_ws, size_t ws_size,
                              hipStream_t stream) {
    const float* emb   = (const float*)d_in[0];
    const int*   src   = (const int*)d_in[1];
    const int*   dst   = (const int*)d_in[2];
    const int*   users = (const int*)d_in[3];
    const int*   pos   = (const int*)d_in[4];
    const int*   neg   = (const int*)d_in[5];
    const int E = in_sizes[1];
    float* out = (float*)d_out;

    unsigned char* hf_a;  hipGetSymbolAddress((void**)&hf_a, HIP_SYMBOL(g_hf8));
    unsigned char* hf_b = hf_a + (size_t)N_NODES * DIM;

    const int STAGE_BLOCKS = (E + 1024 * EDGES_PER_THREAD - 1) / (1024 * EDGES_PER_THREAD);
    stage_buckets<<<STAGE_BLOCKS, 1024, 0, stream>>>(src, dst, E, users, pos, neg);
    finalize_place<<<NBUCKET, 512, 0, stream>>>(emb);

    const int NQUAD = (N_NODES + 3) / 4;           // 4 nodes per wave
    const int PULL_BLOCKS = (NQUAD * 64 + 255) / 256;

    // layer 1: full pull + sampled gather (assign) + bcur reset
    pull_layer_fp8<<<PULL_BLOCKS, 256, 0, stream>>>(hf_a, hf_b, 1);

    // layer 2: full pull + sampled gather (accumulate) + chain consume
    pull_layer_fp8<<<PULL_BLOCKS, 256, 0, stream>>>(hf_b, hf_a, 2);

    // layer 3 sampled pull (4 samples/wave)
    const int SAMP_BLOCKS = ((3 * BATCH + 3) / 4 * 64 + 255) / 256;
    pull_sampled<<<SAMP_BLOCKS, 256, 0, stream>>>(hf_a, users, pos, neg);

    score_reduce<<<(BATCH * 64 + 255) / 256, 256, 0, stream>>>(emb, users, pos, neg);
    final_reduce<<<1, 256, 0, stream>>>(out);
}